// Round 12
// baseline (397.358 us; speedup 1.0000x reference)
//
#include <hip/hip_runtime.h>
#include <hip/hip_bf16.h>

typedef __bf16 bf16;
typedef bf16 bf16x8 __attribute__((ext_vector_type(8)));
typedef float f32x4 __attribute__((ext_vector_type(4)));

static __device__ __forceinline__ f32x4 mfma16(bf16x8 a, bf16x8 b, f32x4 c) {
  return __builtin_amdgcn_mfma_f32_16x16x32_bf16(a, b, c, 0, 0, 0);
}

typedef __attribute__((address_space(3))) void lds_t;
typedef const __attribute__((address_space(1))) void gm_t;

#define N_SEG 18
#define TOTAL_CONV 2511616

struct ConvArgs { const void* src[N_SEG]; };

// canonicalize all 18 inputs -> bf16 arena + p passthrough; dtype flag computed
// per-block from x's exponent distribution (block 0 publishes for tail_k).
__global__ __launch_bounds__(256) void convall_k(ConvArgs a, bf16* __restrict__ dst,
                                                 void* __restrict__ outp,
                                                 int* __restrict__ flag) {
  const int ends[N_SEG] = {2097152, 2146304, 2162688, 2162816, 2228352, 2228864,
                           2294400, 2294912, 2360448, 2360960, 2362496, 2363008,
                           2428544, 2429056, 2494592, 2495104, 2511488, 2511616};
  const unsigned short* xr = (const unsigned short*)a.src[0];
  int wild = 0;
#pragma unroll
  for (int j = 0; j < 2; j++) {
    unsigned short w = xr[threadIdx.x * 2 + j];
    int e = (w >> 7) & 0xFF;
    if (e < 110 || e > 134) wild++;
  }
#pragma unroll
  for (int off = 1; off < 64; off <<= 1) wild += __shfl_xor(wild, off);
  __shared__ int red[4];
  if ((threadIdx.x & 63) == 0) red[threadIdx.x >> 6] = wild;
  __syncthreads();
  const int isF32 = (red[0] + red[1] + red[2] + red[3]) > 64;
  if (blockIdx.x == 0 && threadIdx.x == 0) *flag = isF32;

  int i = blockIdx.x * 256 + threadIdx.x;
  if (i >= TOTAL_CONV) {
    int j = i - TOTAL_CONV;
    if (j < 49152) {
      if (isF32) ((float*)outp)[2097152 + j] = ((const float*)a.src[1])[j];
      else       ((bf16*)outp)[2097152 + j]  = ((const bf16*)a.src[1])[j];
    }
    return;
  }
  int s = 0;
  while (i >= ends[s]) s++;
  int j = i - (s ? ends[s - 1] : 0);
  if (isF32) dst[i] = (bf16)((const float*)a.src[s])[j];
  else       dst[i] = ((const bf16*)a.src[s])[j];
}

// fused pre-attention, 64-row tiles x head. q-epilogue folds scale*log2(e)
// so attn can use exp2 (v_exp_f32 is natively 2^x).
__global__ __launch_bounds__(256, 3) void pre_k(
    const bf16* __restrict__ x, const bf16* __restrict__ p,
    const bf16* __restrict__ f1w, const bf16* __restrict__ f1b,
    const bf16* __restrict__ pe1w, const bf16* __restrict__ pe1b,
    const bf16* __restrict__ pe2w, const bf16* __restrict__ pe2b,
    const bf16* __restrict__ Wq, const bf16* __restrict__ Bq,
    const bf16* __restrict__ Wk, const bf16* __restrict__ Bk,
    const bf16* __restrict__ Wv, const bf16* __restrict__ Bv,
    bf16* __restrict__ qo, bf16* __restrict__ ko, bf16* __restrict__ vo)
{
  const int lane = threadIdx.x & 63;
  const int wave = threadIdx.x >> 6;
  const int quad = lane >> 4;
  const int n15 = lane & 15;
  const int h = blockIdx.y;
  const int r0 = blockIdx.x * 64;
  const int wr = wave * 16;

  __shared__ bf16 tile[9216];   // phase A: [64 rows][136] ; phase B: [128 c][72]

  f32x4 acc[8];
  const f32x4 zz = {};

  // ---- pe1 = relu(p @ pe1w^T + pe1b), K=3 zero-padded MFMA ----
  {
    bf16x8 ap = {};
    if (quad == 0) {
      const bf16* pr = p + (long)(r0 + wr + n15) * 3;
      ap[0] = pr[0]; ap[1] = pr[1]; ap[2] = pr[2];
    }
#pragma unroll
    for (int ct = 0; ct < 8; ct++) {
      bf16x8 bw = {};
      if (quad == 0) {
        const bf16* wp = pe1w + ((long)h * 128 + ct * 16 + n15) * 3;
        bw[0] = wp[0]; bw[1] = wp[1]; bw[2] = wp[2];
      }
      acc[ct] = mfma16(ap, bw, zz);
    }
#pragma unroll
    for (int ct = 0; ct < 8; ct++) {
      const int col = ct * 16 + n15;
      const float bb = (float)pe1b[h * 128 + col];
#pragma unroll
      for (int r = 0; r < 4; r++)
        tile[(wr + quad * 4 + r) * 136 + col] = (bf16)fmaxf(acc[ct][r] + bb, 0.f);
    }
  }

  // ---- xh = pe @ pe2w^T + x @ f1w^T + (pe2b + f1b), single accumulator ----
#pragma unroll
  for (int ct = 0; ct < 8; ct++) acc[ct] = zz;
#pragma unroll
  for (int kk = 0; kk < 4; kk++) {
    const int ka = kk * 32 + quad * 8;
    bf16x8 a0 = *(const bf16x8*)&tile[(wr + n15) * 136 + ka];
#pragma unroll
    for (int ct = 0; ct < 8; ct++) {
      bf16x8 wf = *(const bf16x8*)(pe2w + (long)h * 16384 + (long)(ct * 16 + n15) * 128 + ka);
      acc[ct] = mfma16(a0, wf, acc[ct]);
    }
  }
#pragma unroll
  for (int kk = 0; kk < 4; kk++) {
    const int ka = kk * 32 + quad * 8;
    bf16x8 a0 = *(const bf16x8*)(x + (long)(r0 + wr + n15) * 128 + ka);
#pragma unroll
    for (int ct = 0; ct < 8; ct++) {
      bf16x8 wf = *(const bf16x8*)(f1w + (long)(ct * 16 + n15) * 128 + ka);
      acc[ct] = mfma16(a0, wf, acc[ct]);
    }
  }
#pragma unroll
  for (int ct = 0; ct < 8; ct++) {
    const int col = ct * 16 + n15;
    const float bv = (float)pe2b[h * 128 + col] + (float)f1b[col];
#pragma unroll
    for (int r = 0; r < 4; r++)
      tile[(wr + quad * 4 + r) * 136 + col] = (bf16)(acc[ct][r] + bv);
  }

  // ---- A-frags of xh (wave-local, DS pipe in-order per wave) ----
  bf16x8 af[4];
#pragma unroll
  for (int kk = 0; kk < 4; kk++)
    af[kk] = *(const bf16x8*)&tile[(wr + n15) * 136 + kk * 32 + quad * 8];

  // ---- q (scale*log2e folded) and k ----
#pragma unroll
  for (int m = 0; m < 2; m++) {
    f32x4 a2[8];
#pragma unroll
    for (int ct = 0; ct < 8; ct++) a2[ct] = zz;
    const bf16* Wm = (m == 0) ? Wq : Wk;
#pragma unroll
    for (int kk = 0; kk < 4; kk++) {
      const int ka = kk * 32 + quad * 8;
#pragma unroll
      for (int ct = 0; ct < 8; ct++) {
        bf16x8 wf = *(const bf16x8*)(Wm + (long)h * 16384 + (long)(ct * 16 + n15) * 128 + ka);
        a2[ct] = mfma16(af[kk], wf, a2[ct]);
      }
    }
    bf16* oz = ((m == 0) ? qo : ko) + (long)h * 2097152;
    const bf16* Bz = (m == 0) ? Bq : Bk;
    const float sc = (m == 0) ? 0.12751743f : 1.0f;  // (1/sqrt(128))*log2(e)
#pragma unroll
    for (int ct = 0; ct < 8; ct++) {
      const int col = ct * 16 + n15;
      const float bv = (float)Bz[h * 128 + col];
#pragma unroll
      for (int r = 0; r < 4; r++)
        oz[(long)(r0 + wr + quad * 4 + r) * 128 + col] = (bf16)((a2[ct][r] + bv) * sc);
    }
  }

  // ---- v, transposed store via LDS ----
  {
    f32x4 a2[8];
#pragma unroll
    for (int ct = 0; ct < 8; ct++) a2[ct] = zz;
#pragma unroll
    for (int kk = 0; kk < 4; kk++) {
      const int ka = kk * 32 + quad * 8;
#pragma unroll
      for (int ct = 0; ct < 8; ct++) {
        bf16x8 wf = *(const bf16x8*)(Wv + (long)h * 16384 + (long)(ct * 16 + n15) * 128 + ka);
        a2[ct] = mfma16(af[kk], wf, a2[ct]);
      }
    }
    __syncthreads();   // all waves done with xh tile
#pragma unroll
    for (int ct = 0; ct < 8; ct++) {
      const int col = ct * 16 + n15;
      const float bv = (float)Bv[h * 128 + col];
#pragma unroll
      for (int r = 0; r < 4; r++)
        tile[col * 72 + (wr + quad * 4 + r)] = (bf16)(a2[ct][r] + bv);
    }
    __syncthreads();
    bf16* vz = vo + (long)h * 2097152;
#pragma unroll
    for (int i = 0; i < 16; i++) {
      const int c = wave * 32 + i * 2 + (lane >> 5);
      const int m2 = (lane & 31) * 2;
      *(unsigned int*)&vz[(long)c * 16384 + r0 + m2] =
          *(const unsigned int*)&tile[c * 72 + m2];
    }
  }
}

// flash attention, FAT wave (32 q-rows, 2 row-groups -> kf/vf amortized),
// KV tile 64 single-buffered, KV range split x2. Register diet to reach
// 3 waves/SIMD under launch_bounds(256,3) [unified cap 170 = arch 106 + 64
// AGPR Om]: lds-direct staging (no staging VGPRs), Q frags reloaded from
// global (L2-hot), pf read at point of use. LDS 48KB -> 3 blocks/CU.
__global__ __launch_bounds__(256, 3) void attn_k(
    const bf16* __restrict__ Q, const bf16* __restrict__ Kg,
    const bf16* __restrict__ vT, bf16* __restrict__ Op, float* __restrict__ ls)
{
  const int lane = threadIdx.x & 63;
  const int wave = threadIdx.x >> 6;
  const int quad = lane >> 4;
  const int n15 = lane & 15;
  const int qt = blockIdx.x >> 1;
  const int half = blockIdx.x & 1;
  const int b = blockIdx.y, h = blockIdx.z;
  const long qkBase = ((long)h * 4 + b) * 4096 * 128;
  const long vBase = (long)h * (128L * 16384) + (long)b * 4096;
  const int wrow = qt * 128 + wave * 32;
  const int kvStart = half * 2048;

  __shared__ bf16 Kt[64 * 128];    // addr(kv,c) = kv*128 + ((c>>3 ^ (kv&15))*8) + (c&7)
  __shared__ bf16 Vt[128 * 64];    // addr(c,kv) = c*64  + ((kv>>3 ^ (c&7))*8)  + (kv&7)
  __shared__ bf16 Pt[8][1024];     // [wave*2+g]; addr(r,kv) = r*64 + ((kv>>3 ^ (r&7))*8) + (kv&7)

  const bf16* qrow = Q + qkBase + (long)(wrow + n15) * 128 + quad * 8;

  // async staging lane mapping (fixed per thread)
  const int krl  = lane >> 4;      // K: row within 4-row chunk
  const int kpch = lane & 15;      // K: physical 16B chunk
  const int vcl  = lane >> 3;      // V: c-row within 8-row chunk
  const int vpch = lane & 7;       // V: physical 16B chunk

  f32x4 Om[2][8] = {};
  float l_part[2][4] = {};

  for (int kv0 = kvStart; kv0 < kvStart + 2048; kv0 += 64) {
    __syncthreads();
#pragma unroll
    for (int i = 0; i < 4; i++) {
      const int row = wave * 16 + i * 4 + krl;
      const int ch = kpch ^ (row & 15);
      __builtin_amdgcn_global_load_lds(
          (gm_t*)(Kg + qkBase + (long)(kv0 + row) * 128 + ch * 8),
          (lds_t*)&Kt[(wave * 16 + i * 4) * 128], 16, 0, 0);
    }
#pragma unroll
    for (int i = 0; i < 4; i++) {
      const int c = wave * 32 + i * 8 + vcl;
      const int vch = vpch ^ (c & 7);
      __builtin_amdgcn_global_load_lds(
          (gm_t*)(vT + vBase + (long)c * 16384 + kv0 + vch * 8),
          (lds_t*)&Vt[(wave * 32 + i * 8) * 64], 16, 0, 0);
    }
    __syncthreads();

    // S = Q @ K^T; Q fragments reloaded from global (kf hoisted across groups)
    f32x4 S[2][4] = {};
#pragma unroll
    for (int kk = 0; kk < 4; kk++) {
      bf16x8 q0 = *(const bf16x8*)(qrow + kk * 32);
      bf16x8 q1 = *(const bf16x8*)(qrow + 2048 + kk * 32);
#pragma unroll
      for (int ct = 0; ct < 4; ct++) {
        bf16x8 kf = *(const bf16x8*)&Kt[(ct * 16 + n15) * 128 + (((kk * 4 + quad) ^ n15) * 8)];
        S[0][ct] = mfma16(q0, kf, S[0][ct]);
        S[1][ct] = mfma16(q1, kf, S[1][ct]);
      }
    }

    // exp2 -> per-group Pt slots (read back at point of use)
#pragma unroll
    for (int g = 0; g < 2; g++)
#pragma unroll
      for (int ct = 0; ct < 4; ct++)
#pragma unroll
        for (int r = 0; r < 4; r++) {
          float e = __builtin_amdgcn_exp2f(S[g][ct][r]);
          l_part[g][r] += e;
          const int row = quad * 4 + r;
          const int kv = ct * 16 + n15;
          Pt[wave * 2 + g][row * 64 + ((((kv >> 3) ^ (row & 7)) * 8)) + (kv & 7)] = (bf16)e;
        }

    // O += P @ V, vf hoisted across both row-groups, pf read where used
#pragma unroll
    for (int kk = 0; kk < 2; kk++) {
      bf16x8 vf[8];
#pragma unroll
      for (int ct = 0; ct < 8; ct++) {
        const int c = ct * 16 + n15;
        vf[ct] = *(const bf16x8*)&Vt[c * 64 + (((kk * 4 + quad) ^ (c & 7)) * 8)];
      }
#pragma unroll
      for (int g = 0; g < 2; g++) {
        bf16x8 pf = *(const bf16x8*)&Pt[wave * 2 + g][n15 * 64 + (((kk * 4 + quad) ^ (n15 & 7)) * 8)];
#pragma unroll
        for (int ct = 0; ct < 8; ct++)
          Om[g][ct] = mfma16(pf, vf[ct], Om[g][ct]);
      }
    }
  }

  // unnormalized partial out + row sums
#pragma unroll
  for (int g = 0; g < 2; g++) {
#pragma unroll
    for (int r = 0; r < 4; r++) {
      float s = l_part[g][r];
#pragma unroll
      for (int off = 1; off < 16; off <<= 1) s += __shfl_xor(s, off);
      if (n15 == 0)
        ls[((long)half * 4 + h) * 16384 + b * 4096 + wrow + g * 16 + quad * 4 + r] = s;
    }
    const long ob = (long)half * 8388608 + (long)(b * 4096 + wrow + g * 16 + quad * 4) * 512 + h * 128;
#pragma unroll
    for (int ct = 0; ct < 8; ct++)
#pragma unroll
      for (int r = 0; r < 4; r++)
        Op[ob + (long)r * 512 + ct * 16 + n15] = (bf16)Om[g][ct][r];
  }
}

// fused tail: combine KV halves ((O0+O1)/(l0+l1)) while loading A-frags;
// y1 = . @ mh_w^T + mh_b ; y2 = y1 @ fcl2_w^T + fcl2_b ; LN ; + residual
__global__ __launch_bounds__(256) void tail_k(
    const bf16* __restrict__ Op, const float* __restrict__ ls,
    const bf16* __restrict__ mhw, const bf16* __restrict__ mhb,
    const bf16* __restrict__ f2w, const bf16* __restrict__ f2b,
    const void* __restrict__ xraw, void* __restrict__ outraw,
    const int* __restrict__ flag)
{
  const int lane = threadIdx.x & 63;
  const int wave = threadIdx.x >> 6;
  const int quad = lane >> 4;
  const int n15 = lane & 15;
  const int r0 = blockIdx.x * 64 + wave * 16;
  __shared__ bf16 y1t[64][136];

  float invA[4];
#pragma unroll
  for (int hh = 0; hh < 4; hh++) {
    const float l0 = ls[(long)hh * 16384 + r0 + n15];
    const float l1 = ls[(long)(4 + hh) * 16384 + r0 + n15];
    invA[hh] = 1.f / (l0 + l1);
  }

  f32x4 acc[8] = {};
  for (int k0 = 0; k0 < 512; k0 += 32) {
    const int hh = k0 >> 7;
    const int ka = k0 + quad * 8;
    bf16x8 v0 = *(const bf16x8*)(Op + (long)(r0 + n15) * 512 + ka);
    bf16x8 v1 = *(const bf16x8*)(Op + 8388608L + (long)(r0 + n15) * 512 + ka);
    bf16x8 a0;
#pragma unroll
    for (int j = 0; j < 8; j++)
      a0[j] = (bf16)(((float)v0[j] + (float)v1[j]) * invA[hh]);
#pragma unroll
    for (int ct = 0; ct < 8; ct++) {
      bf16x8 wf = *(const bf16x8*)(mhw + (long)(ct * 16 + n15) * 512 + ka);
      acc[ct] = mfma16(a0, wf, acc[ct]);
    }
  }
#pragma unroll
  for (int ct = 0; ct < 8; ct++) {
    const float bv = (float)mhb[ct * 16 + n15];
#pragma unroll
    for (int r = 0; r < 4; r++)
      y1t[wave * 16 + quad * 4 + r][ct * 16 + n15] = (bf16)(acc[ct][r] + bv);
  }

  f32x4 acc2[8] = {};
  for (int k0 = 0; k0 < 128; k0 += 32) {
    const int ka = k0 + quad * 8;
    bf16x8 a0 = *(const bf16x8*)&y1t[wave * 16 + n15][ka];
#pragma unroll
    for (int ct = 0; ct < 8; ct++) {
      bf16x8 wf = *(const bf16x8*)(f2w + (long)(ct * 16 + n15) * 128 + ka);
      acc2[ct] = mfma16(a0, wf, acc2[ct]);
    }
  }

  float s1[4] = {}, s2[4] = {};
#pragma unroll
  for (int ct = 0; ct < 8; ct++) {
    const float bv = (float)f2b[ct * 16 + n15];
#pragma unroll
    for (int r = 0; r < 4; r++) {
      const float v = acc2[ct][r] + bv;
      acc2[ct][r] = v;
      s1[r] += v;
      s2[r] += v * v;
    }
  }
  float mu[4], inv[4];
#pragma unroll
  for (int r = 0; r < 4; r++) {
    float a = s1[r], b2 = s2[r];
#pragma unroll
    for (int off = 1; off < 16; off <<= 1) {
      a += __shfl_xor(a, off);
      b2 += __shfl_xor(b2, off);
    }
    mu[r] = a * (1.f / 128.f);
    const float var = fmaxf(b2 * (1.f / 128.f) - mu[r] * mu[r], 0.f);
    inv[r] = rsqrtf(var + 1e-5f);
  }

  const int isF32 = *flag;
#pragma unroll
  for (int ct = 0; ct < 8; ct++)
#pragma unroll
    for (int r = 0; r < 4; r++) {
      const long idx = (long)(r0 + quad * 4 + r) * 128 + ct * 16 + n15;
      const float resid = isF32 ? ((const float*)xraw)[idx]
                                : (float)((const bf16*)xraw)[idx];
      const float v = (acc2[ct][r] - mu[r]) * inv[r] + resid;
      if (isF32) ((float*)outraw)[idx] = v;
      else       ((bf16*)outraw)[idx] = (bf16)v;
    }
}

extern "C" void kernel_launch(void* const* d_in, const int* in_sizes, int n_in,
                              void* d_out, int out_size, void* d_ws, size_t ws_size,
                              hipStream_t stream)
{
  bf16* ws  = (bf16*)d_ws;
  bf16* q   = ws;                     // 8388608 elems [h][m][c]
  bf16* kb  = ws + 8388608;           // 8388608
  bf16* vt  = ws + 16777216;          // 8388608 (vT[h][c][m])
  bf16* Op  = ws + 25165824;          // 16777216 ([half][m][512])
  float* lsb = (float*)(ws + 41943040);  // 131072 f32 ([half][h][m])
  const long AR = 42205184;           // bf16 canonical arena (2511616 elems)
  int* flag = (int*)(ws + 44720000);

  static const int counts[N_SEG] = {2097152, 49152, 16384, 128, 65536, 512, 65536, 512,
                                    65536, 512, 1536, 512, 65536, 512, 65536, 512, 16384, 128};
  long offs[N_SEG]; long o = AR;
  for (int i = 0; i < N_SEG; i++) { offs[i] = o; o += counts[i]; }
  bf16* xc    = ws + offs[0];
  bf16* pc    = ws + offs[1];
  bf16* f1w   = ws + offs[2];
  bf16* f1b   = ws + offs[3];
  bf16* hqw   = ws + offs[4];
  bf16* hqb   = ws + offs[5];
  bf16* hkw   = ws + offs[6];
  bf16* hkb   = ws + offs[7];
  bf16* hvw   = ws + offs[8];
  bf16* hvb   = ws + offs[9];
  bf16* pe1w  = ws + offs[10];
  bf16* pe1b  = ws + offs[11];
  bf16* pe2w  = ws + offs[12];
  bf16* pe2b  = ws + offs[13];
  bf16* mhw   = ws + offs[14];
  bf16* mhb   = ws + offs[15];
  bf16* f2w   = ws + offs[16];
  bf16* f2b   = ws + offs[17];

  ConvArgs ca;
  for (int i = 0; i < N_SEG; i++) ca.src[i] = d_in[i];
  convall_k<<<dim3((TOTAL_CONV + 49152 + 255) / 256), dim3(256), 0, stream>>>(ca, ws + AR, d_out, flag);

  dim3 blk(256);
  // q uses hk_w, k uses hq_w (reference name swap)
  pre_k<<<dim3(256, 4), blk, 0, stream>>>(xc, pc, f1w, f1b, pe1w, pe1b, pe2w, pe2b,
                                          hkw, hkb, hqw, hqb, hvw, hvb, q, kb, vt);
  attn_k<<<dim3(64, 4, 4), blk, 0, stream>>>(q, kb, vt, Op, lsb);
  tail_k<<<dim3(256), blk, 0, stream>>>(Op, lsb, mhw, mhb, f2w, f2b, d_in[0], d_out, flag);
}

// Round 13
// 358.188 us; speedup vs baseline: 1.1094x; 1.1094x over previous
//
#include <hip/hip_runtime.h>
#include <hip/hip_bf16.h>

typedef __bf16 bf16;
typedef bf16 bf16x8 __attribute__((ext_vector_type(8)));
typedef float f32x4 __attribute__((ext_vector_type(4)));

static __device__ __forceinline__ f32x4 mfma16(bf16x8 a, bf16x8 b, f32x4 c) {
  return __builtin_amdgcn_mfma_f32_16x16x32_bf16(a, b, c, 0, 0, 0);
}

typedef __attribute__((address_space(3))) void lds_t;
typedef const __attribute__((address_space(1))) void gm_t;

#define N_SEG 18
#define TOTAL_CONV 2511616

struct ConvArgs { const void* src[N_SEG]; };

// canonicalize all 18 inputs -> bf16 arena + p passthrough; dtype flag computed
// per-block from x's exponent distribution (block 0 publishes for tail_k).
__global__ __launch_bounds__(256) void convall_k(ConvArgs a, bf16* __restrict__ dst,
                                                 void* __restrict__ outp,
                                                 int* __restrict__ flag) {
  const int ends[N_SEG] = {2097152, 2146304, 2162688, 2162816, 2228352, 2228864,
                           2294400, 2294912, 2360448, 2360960, 2362496, 2363008,
                           2428544, 2429056, 2494592, 2495104, 2511488, 2511616};
  const unsigned short* xr = (const unsigned short*)a.src[0];
  int wild = 0;
#pragma unroll
  for (int j = 0; j < 2; j++) {
    unsigned short w = xr[threadIdx.x * 2 + j];
    int e = (w >> 7) & 0xFF;
    if (e < 110 || e > 134) wild++;
  }
#pragma unroll
  for (int off = 1; off < 64; off <<= 1) wild += __shfl_xor(wild, off);
  __shared__ int red[4];
  if ((threadIdx.x & 63) == 0) red[threadIdx.x >> 6] = wild;
  __syncthreads();
  const int isF32 = (red[0] + red[1] + red[2] + red[3]) > 64;
  if (blockIdx.x == 0 && threadIdx.x == 0) *flag = isF32;

  int i = blockIdx.x * 256 + threadIdx.x;
  if (i >= TOTAL_CONV) {
    int j = i - TOTAL_CONV;
    if (j < 49152) {
      if (isF32) ((float*)outp)[2097152 + j] = ((const float*)a.src[1])[j];
      else       ((bf16*)outp)[2097152 + j]  = ((const bf16*)a.src[1])[j];
    }
    return;
  }
  int s = 0;
  while (i >= ends[s]) s++;
  int j = i - (s ? ends[s - 1] : 0);
  if (isF32) dst[i] = (bf16)((const float*)a.src[s])[j];
  else       dst[i] = ((const bf16*)a.src[s])[j];
}

// fused pre-attention, 64-row tiles x head. q-epilogue folds scale*log2(e)
// so attn can use exp2 (v_exp_f32 is natively 2^x).
__global__ __launch_bounds__(256, 2) void pre_k(
    const bf16* __restrict__ x, const bf16* __restrict__ p,
    const bf16* __restrict__ f1w, const bf16* __restrict__ f1b,
    const bf16* __restrict__ pe1w, const bf16* __restrict__ pe1b,
    const bf16* __restrict__ pe2w, const bf16* __restrict__ pe2b,
    const bf16* __restrict__ Wq, const bf16* __restrict__ Bq,
    const bf16* __restrict__ Wk, const bf16* __restrict__ Bk,
    const bf16* __restrict__ Wv, const bf16* __restrict__ Bv,
    bf16* __restrict__ qo, bf16* __restrict__ ko, bf16* __restrict__ vo)
{
  const int lane = threadIdx.x & 63;
  const int wave = threadIdx.x >> 6;
  const int quad = lane >> 4;
  const int n15 = lane & 15;
  const int h = blockIdx.y;
  const int r0 = blockIdx.x * 64;
  const int wr = wave * 16;

  __shared__ bf16 tile[9216];   // phase A: [64 rows][136] ; phase B: [128 c][72]

  f32x4 acc[8];
  const f32x4 zz = {};

  // ---- pe1 = relu(p @ pe1w^T + pe1b), K=3 zero-padded MFMA ----
  {
    bf16x8 ap = {};
    if (quad == 0) {
      const bf16* pr = p + (long)(r0 + wr + n15) * 3;
      ap[0] = pr[0]; ap[1] = pr[1]; ap[2] = pr[2];
    }
#pragma unroll
    for (int ct = 0; ct < 8; ct++) {
      bf16x8 bw = {};
      if (quad == 0) {
        const bf16* wp = pe1w + ((long)h * 128 + ct * 16 + n15) * 3;
        bw[0] = wp[0]; bw[1] = wp[1]; bw[2] = wp[2];
      }
      acc[ct] = mfma16(ap, bw, zz);
    }
#pragma unroll
    for (int ct = 0; ct < 8; ct++) {
      const int col = ct * 16 + n15;
      const float bb = (float)pe1b[h * 128 + col];
#pragma unroll
      for (int r = 0; r < 4; r++)
        tile[(wr + quad * 4 + r) * 136 + col] = (bf16)fmaxf(acc[ct][r] + bb, 0.f);
    }
  }

  // ---- xh = pe @ pe2w^T + x @ f1w^T + (pe2b + f1b), single accumulator ----
#pragma unroll
  for (int ct = 0; ct < 8; ct++) acc[ct] = zz;
#pragma unroll
  for (int kk = 0; kk < 4; kk++) {
    const int ka = kk * 32 + quad * 8;
    bf16x8 a0 = *(const bf16x8*)&tile[(wr + n15) * 136 + ka];
#pragma unroll
    for (int ct = 0; ct < 8; ct++) {
      bf16x8 wf = *(const bf16x8*)(pe2w + (long)h * 16384 + (long)(ct * 16 + n15) * 128 + ka);
      acc[ct] = mfma16(a0, wf, acc[ct]);
    }
  }
#pragma unroll
  for (int kk = 0; kk < 4; kk++) {
    const int ka = kk * 32 + quad * 8;
    bf16x8 a0 = *(const bf16x8*)(x + (long)(r0 + wr + n15) * 128 + ka);
#pragma unroll
    for (int ct = 0; ct < 8; ct++) {
      bf16x8 wf = *(const bf16x8*)(f1w + (long)(ct * 16 + n15) * 128 + ka);
      acc[ct] = mfma16(a0, wf, acc[ct]);
    }
  }
#pragma unroll
  for (int ct = 0; ct < 8; ct++) {
    const int col = ct * 16 + n15;
    const float bv = (float)pe2b[h * 128 + col] + (float)f1b[col];
#pragma unroll
    for (int r = 0; r < 4; r++)
      tile[(wr + quad * 4 + r) * 136 + col] = (bf16)(acc[ct][r] + bv);
  }

  // ---- A-frags of xh (wave-local, DS pipe in-order per wave) ----
  bf16x8 af[4];
#pragma unroll
  for (int kk = 0; kk < 4; kk++)
    af[kk] = *(const bf16x8*)&tile[(wr + n15) * 136 + kk * 32 + quad * 8];

  // ---- q (scale*log2e folded) and k ----
#pragma unroll
  for (int m = 0; m < 2; m++) {
    f32x4 a2[8];
#pragma unroll
    for (int ct = 0; ct < 8; ct++) a2[ct] = zz;
    const bf16* Wm = (m == 0) ? Wq : Wk;
#pragma unroll
    for (int kk = 0; kk < 4; kk++) {
      const int ka = kk * 32 + quad * 8;
#pragma unroll
      for (int ct = 0; ct < 8; ct++) {
        bf16x8 wf = *(const bf16x8*)(Wm + (long)h * 16384 + (long)(ct * 16 + n15) * 128 + ka);
        a2[ct] = mfma16(af[kk], wf, a2[ct]);
      }
    }
    bf16* oz = ((m == 0) ? qo : ko) + (long)h * 2097152;
    const bf16* Bz = (m == 0) ? Bq : Bk;
    const float sc = (m == 0) ? 0.12751743f : 1.0f;  // (1/sqrt(128))*log2(e)
#pragma unroll
    for (int ct = 0; ct < 8; ct++) {
      const int col = ct * 16 + n15;
      const float bv = (float)Bz[h * 128 + col];
#pragma unroll
      for (int r = 0; r < 4; r++)
        oz[(long)(r0 + wr + quad * 4 + r) * 128 + col] = (bf16)((a2[ct][r] + bv) * sc);
    }
  }

  // ---- v, transposed store via LDS ----
  {
    f32x4 a2[8];
#pragma unroll
    for (int ct = 0; ct < 8; ct++) a2[ct] = zz;
#pragma unroll
    for (int kk = 0; kk < 4; kk++) {
      const int ka = kk * 32 + quad * 8;
#pragma unroll
      for (int ct = 0; ct < 8; ct++) {
        bf16x8 wf = *(const bf16x8*)(Wv + (long)h * 16384 + (long)(ct * 16 + n15) * 128 + ka);
        a2[ct] = mfma16(af[kk], wf, a2[ct]);
      }
    }
    __syncthreads();   // all waves done with xh tile
#pragma unroll
    for (int ct = 0; ct < 8; ct++) {
      const int col = ct * 16 + n15;
      const float bv = (float)Bv[h * 128 + col];
#pragma unroll
      for (int r = 0; r < 4; r++)
        tile[col * 72 + (wr + quad * 4 + r)] = (bf16)(a2[ct][r] + bv);
    }
    __syncthreads();
    bf16* vz = vo + (long)h * 2097152;
#pragma unroll
    for (int i = 0; i < 16; i++) {
      const int c = wave * 32 + i * 2 + (lane >> 5);
      const int m2 = (lane & 31) * 2;
      *(unsigned int*)&vz[(long)c * 16384 + r0 + m2] =
          *(const unsigned int*)&tile[c * 72 + m2];
    }
  }
}

// flash attention, FAT wave (32 q-rows/wave, 2 row-groups, kf/vf amortized),
// KV tile 64, DOUBLE-BUFFERED lds-direct staging, NO KV split: full sweep,
// normalize + write cat in-kernel. launch_bounds(256,2): register-pinned
// 2 waves/SIMD (rounds 7-12 evidence); LDS 80KB -> 2 blocks/CU = full
// residency at grid 512. exp2 softmax (log2e folded into q by pre_k).
__global__ __launch_bounds__(256, 2) void attn_k(
    const bf16* __restrict__ Q, const bf16* __restrict__ Kg,
    const bf16* __restrict__ vT, bf16* __restrict__ cat)
{
  const int lane = threadIdx.x & 63;
  const int wave = threadIdx.x >> 6;
  const int quad = lane >> 4;
  const int n15 = lane & 15;
  const int b = blockIdx.y, h = blockIdx.z;
  const long qkBase = ((long)h * 4 + b) * 4096 * 128;
  const long vBase = (long)h * (128L * 16384) + (long)b * 4096;
  const int wrow = blockIdx.x * 128 + wave * 32;

  __shared__ bf16 Kt[2][64 * 128];  // addr(kv,c) = kv*128 + ((c>>3 ^ (kv&15))*8) + (c&7)
  __shared__ bf16 Vt[2][128 * 64];  // addr(c,kv) = c*64  + ((kv>>3 ^ (c&7))*8)  + (kv&7)
  __shared__ bf16 Pt[8][1024];      // [wave*2+g]; addr(r,kv) = r*64 + ((kv>>3 ^ (r&7))*8) + (kv&7)

  // Q fragments once (scale*log2e already folded by pre_k)
  bf16x8 qf[2][4];
#pragma unroll
  for (int g = 0; g < 2; g++)
#pragma unroll
    for (int kk = 0; kk < 4; kk++)
      qf[g][kk] = *(const bf16x8*)(Q + qkBase + (long)(wrow + g * 16 + n15) * 128 + kk * 32 + quad * 8);

  // async staging lane mapping (fixed per thread)
  const int krl  = lane >> 4;      // K: row within 4-row chunk
  const int kpch = lane & 15;      // K: physical 16B chunk
  const int vcl  = lane >> 3;      // V: c-row within 8-row chunk
  const int vpch = lane & 7;       // V: physical 16B chunk

  f32x4 Om[2][8] = {};
  float l_part[2][4] = {};

  // prefetch tile 0 into buffer 0
#pragma unroll
  for (int i = 0; i < 4; i++) {
    const int row = wave * 16 + i * 4 + krl;
    const int ch = kpch ^ (row & 15);
    __builtin_amdgcn_global_load_lds(
        (gm_t*)(Kg + qkBase + (long)row * 128 + ch * 8),
        (lds_t*)&Kt[0][(wave * 16 + i * 4) * 128], 16, 0, 0);
  }
#pragma unroll
  for (int i = 0; i < 4; i++) {
    const int c = wave * 32 + i * 8 + vcl;
    const int vch = vpch ^ (c & 7);
    __builtin_amdgcn_global_load_lds(
        (gm_t*)(vT + vBase + (long)c * 16384 + vch * 8),
        (lds_t*)&Vt[0][(wave * 32 + i * 8) * 64], 16, 0, 0);
  }

  for (int it = 0; it < 64; it++) {
    __syncthreads();   // drains prefetch(it) issued one full compute phase ago
    const int cb = it & 1;
    if (it + 1 < 64) {
      const int kv1 = (it + 1) * 64;
      const int nb = cb ^ 1;
#pragma unroll
      for (int i = 0; i < 4; i++) {
        const int row = wave * 16 + i * 4 + krl;
        const int ch = kpch ^ (row & 15);
        __builtin_amdgcn_global_load_lds(
            (gm_t*)(Kg + qkBase + (long)(kv1 + row) * 128 + ch * 8),
            (lds_t*)&Kt[nb][(wave * 16 + i * 4) * 128], 16, 0, 0);
      }
#pragma unroll
      for (int i = 0; i < 4; i++) {
        const int c = wave * 32 + i * 8 + vcl;
        const int vch = vpch ^ (c & 7);
        __builtin_amdgcn_global_load_lds(
            (gm_t*)(vT + vBase + (long)c * 16384 + kv1 + vch * 8),
            (lds_t*)&Vt[nb][(wave * 32 + i * 8) * 64], 16, 0, 0);
      }
    }

    // S = Q @ K^T, kf hoisted across both row-groups
    f32x4 S[2][4] = {};
#pragma unroll
    for (int kk = 0; kk < 4; kk++) {
#pragma unroll
      for (int ct = 0; ct < 4; ct++) {
        bf16x8 kf = *(const bf16x8*)&Kt[cb][(ct * 16 + n15) * 128 + (((kk * 4 + quad) ^ n15) * 8)];
        S[0][ct] = mfma16(qf[0][kk], kf, S[0][ct]);
        S[1][ct] = mfma16(qf[1][kk], kf, S[1][ct]);
      }
    }

    // exp2 -> per-group Pt slots
#pragma unroll
    for (int g = 0; g < 2; g++)
#pragma unroll
      for (int ct = 0; ct < 4; ct++)
#pragma unroll
        for (int r = 0; r < 4; r++) {
          float e = __builtin_amdgcn_exp2f(S[g][ct][r]);
          l_part[g][r] += e;
          const int row = quad * 4 + r;
          const int kv = ct * 16 + n15;
          Pt[wave * 2 + g][row * 64 + ((((kv >> 3) ^ (row & 7)) * 8)) + (kv & 7)] = (bf16)e;
        }

    // O += P @ V, vf hoisted across both row-groups, pf read where used
#pragma unroll
    for (int kk = 0; kk < 2; kk++) {
      bf16x8 vf[8];
#pragma unroll
      for (int ct = 0; ct < 8; ct++) {
        const int c = ct * 16 + n15;
        vf[ct] = *(const bf16x8*)&Vt[cb][c * 64 + (((kk * 4 + quad) ^ (c & 7)) * 8)];
      }
#pragma unroll
      for (int g = 0; g < 2; g++) {
        bf16x8 pf = *(const bf16x8*)&Pt[wave * 2 + g][n15 * 64 + (((kk * 4 + quad) ^ (n15 & 7)) * 8)];
#pragma unroll
        for (int ct = 0; ct < 8; ct++)
          Om[g][ct] = mfma16(pf, vf[ct], Om[g][ct]);
      }
    }
  }

  // normalize + write concat layout
#pragma unroll
  for (int g = 0; g < 2; g++) {
    float inv[4];
#pragma unroll
    for (int r = 0; r < 4; r++) {
      float s = l_part[g][r];
#pragma unroll
      for (int off = 1; off < 16; off <<= 1) s += __shfl_xor(s, off);
      inv[r] = 1.f / s;
    }
    const long ob = ((long)b * 4096 + wrow + g * 16 + quad * 4) * 512 + h * 128;
#pragma unroll
    for (int ct = 0; ct < 8; ct++)
#pragma unroll
      for (int r = 0; r < 4; r++)
        cat[ob + (long)r * 512 + ct * 16 + n15] = (bf16)(Om[g][ct][r] * inv[r]);
  }
}

// fused tail: y1 = cat @ mh_w^T + mh_b ; y2 = y1 @ fcl2_w^T + fcl2_b ; LN ; + residual
__global__ __launch_bounds__(256) void tail_k(
    const bf16* __restrict__ cat,
    const bf16* __restrict__ mhw, const bf16* __restrict__ mhb,
    const bf16* __restrict__ f2w, const bf16* __restrict__ f2b,
    const void* __restrict__ xraw, void* __restrict__ outraw,
    const int* __restrict__ flag)
{
  const int lane = threadIdx.x & 63;
  const int wave = threadIdx.x >> 6;
  const int quad = lane >> 4;
  const int n15 = lane & 15;
  const int r0 = blockIdx.x * 64 + wave * 16;
  __shared__ bf16 y1t[64][136];

  f32x4 acc[8] = {};
  for (int k0 = 0; k0 < 512; k0 += 32) {
    const int ka = k0 + quad * 8;
    bf16x8 a0 = *(const bf16x8*)(cat + (long)(r0 + n15) * 512 + ka);
#pragma unroll
    for (int ct = 0; ct < 8; ct++) {
      bf16x8 wf = *(const bf16x8*)(mhw + (long)(ct * 16 + n15) * 512 + ka);
      acc[ct] = mfma16(a0, wf, acc[ct]);
    }
  }
#pragma unroll
  for (int ct = 0; ct < 8; ct++) {
    const float bv = (float)mhb[ct * 16 + n15];
#pragma unroll
    for (int r = 0; r < 4; r++)
      y1t[wave * 16 + quad * 4 + r][ct * 16 + n15] = (bf16)(acc[ct][r] + bv);
  }

  f32x4 acc2[8] = {};
  for (int k0 = 0; k0 < 128; k0 += 32) {
    const int ka = k0 + quad * 8;
    bf16x8 a0 = *(const bf16x8*)&y1t[wave * 16 + n15][ka];
#pragma unroll
    for (int ct = 0; ct < 8; ct++) {
      bf16x8 wf = *(const bf16x8*)(f2w + (long)(ct * 16 + n15) * 128 + ka);
      acc2[ct] = mfma16(a0, wf, acc2[ct]);
    }
  }

  float s1[4] = {}, s2[4] = {};
#pragma unroll
  for (int ct = 0; ct < 8; ct++) {
    const float bv = (float)f2b[ct * 16 + n15];
#pragma unroll
    for (int r = 0; r < 4; r++) {
      const float v = acc2[ct][r] + bv;
      acc2[ct][r] = v;
      s1[r] += v;
      s2[r] += v * v;
    }
  }
  float mu[4], inv[4];
#pragma unroll
  for (int r = 0; r < 4; r++) {
    float a = s1[r], b2 = s2[r];
#pragma unroll
    for (int off = 1; off < 16; off <<= 1) {
      a += __shfl_xor(a, off);
      b2 += __shfl_xor(b2, off);
    }
    mu[r] = a * (1.f / 128.f);
    const float var = fmaxf(b2 * (1.f / 128.f) - mu[r] * mu[r], 0.f);
    inv[r] = rsqrtf(var + 1e-5f);
  }

  const int isF32 = *flag;
#pragma unroll
  for (int ct = 0; ct < 8; ct++)
#pragma unroll
    for (int r = 0; r < 4; r++) {
      const long idx = (long)(r0 + quad * 4 + r) * 128 + ct * 16 + n15;
      const float resid = isF32 ? ((const float*)xraw)[idx]
                                : (float)((const bf16*)xraw)[idx];
      const float v = (acc2[ct][r] - mu[r]) * inv[r] + resid;
      if (isF32) ((float*)outraw)[idx] = v;
      else       ((bf16*)outraw)[idx] = (bf16)v;
    }
}

extern "C" void kernel_launch(void* const* d_in, const int* in_sizes, int n_in,
                              void* d_out, int out_size, void* d_ws, size_t ws_size,
                              hipStream_t stream)
{
  bf16* ws  = (bf16*)d_ws;
  bf16* q   = ws;                     // 8388608 elems [h][m][c]
  bf16* kb  = ws + 8388608;           // 8388608
  bf16* vt  = ws + 16777216;          // 8388608 (vT[h][c][m])
  bf16* cat = ws + 25165824;          // 8388608 (16384 x 512)
  const long AR = 33554432;           // bf16 canonical arena (2511616 elems)
  int* flag = (int*)(ws + 36066048);

  static const int counts[N_SEG] = {2097152, 49152, 16384, 128, 65536, 512, 65536, 512,
                                    65536, 512, 1536, 512, 65536, 512, 65536, 512, 16384, 128};
  long offs[N_SEG]; long o = AR;
  for (int i = 0; i < N_SEG; i++) { offs[i] = o; o += counts[i]; }
  bf16* xc    = ws + offs[0];
  bf16* pc    = ws + offs[1];
  bf16* f1w   = ws + offs[2];
  bf16* f1b   = ws + offs[3];
  bf16* hqw   = ws + offs[4];
  bf16* hqb   = ws + offs[5];
  bf16* hkw   = ws + offs[6];
  bf16* hkb   = ws + offs[7];
  bf16* hvw   = ws + offs[8];
  bf16* hvb   = ws + offs[9];
  bf16* pe1w  = ws + offs[10];
  bf16* pe1b  = ws + offs[11];
  bf16* pe2w  = ws + offs[12];
  bf16* pe2b  = ws + offs[13];
  bf16* mhw   = ws + offs[14];
  bf16* mhb   = ws + offs[15];
  bf16* f2w   = ws + offs[16];
  bf16* f2b   = ws + offs[17];

  ConvArgs ca;
  for (int i = 0; i < N_SEG; i++) ca.src[i] = d_in[i];
  convall_k<<<dim3((TOTAL_CONV + 49152 + 255) / 256), dim3(256), 0, stream>>>(ca, ws + AR, d_out, flag);

  dim3 blk(256);
  // q uses hk_w, k uses hq_w (reference name swap)
  pre_k<<<dim3(256, 4), blk, 0, stream>>>(xc, pc, f1w, f1b, pe1w, pe1b, pe2w, pe2b,
                                          hkw, hkb, hqw, hqb, hvw, hvb, q, kb, vt);
  attn_k<<<dim3(32, 4, 4), blk, 0, stream>>>(q, kb, vt, cat);
  tail_k<<<dim3(256), blk, 0, stream>>>(cat, mhw, mhb, f2w, f2b, d_in[0], d_out, flag);
}

// Round 14
// 328.596 us; speedup vs baseline: 1.2093x; 1.0901x over previous
//
#include <hip/hip_runtime.h>
#include <hip/hip_bf16.h>

typedef __bf16 bf16;
typedef bf16 bf16x8 __attribute__((ext_vector_type(8)));
typedef float f32x4 __attribute__((ext_vector_type(4)));

static __device__ __forceinline__ f32x4 mfma16(bf16x8 a, bf16x8 b, f32x4 c) {
  return __builtin_amdgcn_mfma_f32_16x16x32_bf16(a, b, c, 0, 0, 0);
}

typedef __attribute__((address_space(3))) void lds_t;
typedef const __attribute__((address_space(1))) void gm_t;

#define N_SEG 18
#define TOTAL_CONV 2511616

struct ConvArgs { const void* src[N_SEG]; };

// canonicalize all 18 inputs -> bf16 arena + p passthrough; 8 elems/thread
// (all segment sizes are multiples of 128, so an aligned 8-chunk never
// straddles). dtype flag probed per-block; block 0 publishes for tail_k.
__global__ __launch_bounds__(256) void convall_k(ConvArgs a, bf16* __restrict__ dst,
                                                 void* __restrict__ outp,
                                                 int* __restrict__ flag) {
  const int ends[N_SEG] = {2097152, 2146304, 2162688, 2162816, 2228352, 2228864,
                           2294400, 2294912, 2360448, 2360960, 2362496, 2363008,
                           2428544, 2429056, 2494592, 2495104, 2511488, 2511616};
  const unsigned short* xr = (const unsigned short*)a.src[0];
  int wild = 0;
#pragma unroll
  for (int j = 0; j < 2; j++) {
    unsigned short w = xr[threadIdx.x * 2 + j];
    int e = (w >> 7) & 0xFF;
    if (e < 110 || e > 134) wild++;
  }
#pragma unroll
  for (int off = 1; off < 64; off <<= 1) wild += __shfl_xor(wild, off);
  __shared__ int red[4];
  if ((threadIdx.x & 63) == 0) red[threadIdx.x >> 6] = wild;
  __syncthreads();
  const int isF32 = (red[0] + red[1] + red[2] + red[3]) > 64;
  if (blockIdx.x == 0 && threadIdx.x == 0) *flag = isF32;

  long i = ((long)blockIdx.x * 256 + threadIdx.x) * 8;
  if (i >= TOTAL_CONV) {
    long j = i - TOTAL_CONV;
    if (j < 49152) {
      if (isF32) {
#pragma unroll
        for (int t = 0; t < 8; t++)
          ((float*)outp)[2097152 + j + t] = ((const float*)a.src[1])[j + t];
      } else {
        *(bf16x8*)&((bf16*)outp)[2097152 + j] = *(const bf16x8*)&((const bf16*)a.src[1])[j];
      }
    }
    return;
  }
  int s = 0;
  while (i >= ends[s]) s++;
  long j = i - (s ? ends[s - 1] : 0);
  if (isF32) {
    bf16x8 v;
#pragma unroll
    for (int t = 0; t < 8; t++) v[t] = (bf16)((const float*)a.src[s])[j + t];
    *(bf16x8*)&dst[i] = v;
  } else {
    *(bf16x8*)&dst[i] = *(const bf16x8*)&((const bf16*)a.src[s])[j];
  }
}

// fused pre-attention, 128-row tiles x head (512 blocks): fat waves (32 rows,
// 2 row-groups) so every weight fragment feeds 2 MFMAs; pe1 via K=3 MFMA;
// fcl1+pe2 share one accumulator; q-epilogue folds scale*log2(e); vT stored
// coalesced via LDS transpose.
__global__ __launch_bounds__(256, 2) void pre_k(
    const bf16* __restrict__ x, const bf16* __restrict__ p,
    const bf16* __restrict__ f1w, const bf16* __restrict__ f1b,
    const bf16* __restrict__ pe1w, const bf16* __restrict__ pe1b,
    const bf16* __restrict__ pe2w, const bf16* __restrict__ pe2b,
    const bf16* __restrict__ Wq, const bf16* __restrict__ Bq,
    const bf16* __restrict__ Wk, const bf16* __restrict__ Bk,
    const bf16* __restrict__ Wv, const bf16* __restrict__ Bv,
    bf16* __restrict__ qo, bf16* __restrict__ ko, bf16* __restrict__ vo)
{
  const int lane = threadIdx.x & 63;
  const int wave = threadIdx.x >> 6;
  const int quad = lane >> 4;
  const int n15 = lane & 15;
  const int h = blockIdx.y;
  const int r0 = blockIdx.x * 128;
  const int wr = wave * 32;

  __shared__ bf16 tile[128 * 136];   // row-major [128][136]; later col-major [128c][m]

  f32x4 acc[2][8];
  const f32x4 zz = {};

  // ---- pe1 = relu(p @ pe1w^T + pe1b), K=3 zero-padded MFMA, bw shared over groups ----
  {
    bf16x8 ap0 = {}, ap1 = {};
    if (quad == 0) {
      const bf16* pr0 = p + (long)(r0 + wr + n15) * 3;
      const bf16* pr1 = p + (long)(r0 + wr + 16 + n15) * 3;
      ap0[0] = pr0[0]; ap0[1] = pr0[1]; ap0[2] = pr0[2];
      ap1[0] = pr1[0]; ap1[1] = pr1[1]; ap1[2] = pr1[2];
    }
#pragma unroll
    for (int ct = 0; ct < 8; ct++) {
      bf16x8 bw = {};
      if (quad == 0) {
        const bf16* wp = pe1w + ((long)h * 128 + ct * 16 + n15) * 3;
        bw[0] = wp[0]; bw[1] = wp[1]; bw[2] = wp[2];
      }
      acc[0][ct] = mfma16(ap0, bw, zz);
      acc[1][ct] = mfma16(ap1, bw, zz);
    }
#pragma unroll
    for (int g = 0; g < 2; g++)
#pragma unroll
      for (int ct = 0; ct < 8; ct++) {
        const int col = ct * 16 + n15;
        const float bb = (float)pe1b[h * 128 + col];
#pragma unroll
        for (int r = 0; r < 4; r++)
          tile[(wr + g * 16 + quad * 4 + r) * 136 + col] = (bf16)fmaxf(acc[g][ct][r] + bb, 0.f);
      }
  }

  // ---- xh = pe @ pe2w^T + x @ f1w^T + (pe2b + f1b), single accumulator ----
#pragma unroll
  for (int g = 0; g < 2; g++)
#pragma unroll
    for (int ct = 0; ct < 8; ct++) acc[g][ct] = zz;
#pragma unroll
  for (int kk = 0; kk < 4; kk++) {
    const int ka = kk * 32 + quad * 8;
    bf16x8 a0 = *(const bf16x8*)&tile[(wr + n15) * 136 + ka];
    bf16x8 a1 = *(const bf16x8*)&tile[(wr + 16 + n15) * 136 + ka];
#pragma unroll
    for (int ct = 0; ct < 8; ct++) {
      bf16x8 wf = *(const bf16x8*)(pe2w + (long)h * 16384 + (long)(ct * 16 + n15) * 128 + ka);
      acc[0][ct] = mfma16(a0, wf, acc[0][ct]);
      acc[1][ct] = mfma16(a1, wf, acc[1][ct]);
    }
  }
#pragma unroll
  for (int kk = 0; kk < 4; kk++) {
    const int ka = kk * 32 + quad * 8;
    bf16x8 a0 = *(const bf16x8*)(x + (long)(r0 + wr + n15) * 128 + ka);
    bf16x8 a1 = *(const bf16x8*)(x + (long)(r0 + wr + 16 + n15) * 128 + ka);
#pragma unroll
    for (int ct = 0; ct < 8; ct++) {
      bf16x8 wf = *(const bf16x8*)(f1w + (long)(ct * 16 + n15) * 128 + ka);
      acc[0][ct] = mfma16(a0, wf, acc[0][ct]);
      acc[1][ct] = mfma16(a1, wf, acc[1][ct]);
    }
  }
#pragma unroll
  for (int g = 0; g < 2; g++)
#pragma unroll
    for (int ct = 0; ct < 8; ct++) {
      const int col = ct * 16 + n15;
      const float bv = (float)pe2b[h * 128 + col] + (float)f1b[col];
#pragma unroll
      for (int r = 0; r < 4; r++)
        tile[(wr + g * 16 + quad * 4 + r) * 136 + col] = (bf16)(acc[g][ct][r] + bv);
    }

  // ---- A-frags of xh (wave-local rows; DS pipe in-order per wave) ----
  bf16x8 af[2][4];
#pragma unroll
  for (int g = 0; g < 2; g++)
#pragma unroll
    for (int kk = 0; kk < 4; kk++)
      af[g][kk] = *(const bf16x8*)&tile[(wr + g * 16 + n15) * 136 + kk * 32 + quad * 8];

  // ---- q (scale*log2e folded) and k; wf shared across groups ----
#pragma unroll
  for (int m = 0; m < 2; m++) {
#pragma unroll
    for (int g = 0; g < 2; g++)
#pragma unroll
      for (int ct = 0; ct < 8; ct++) acc[g][ct] = zz;
    const bf16* Wm = (m == 0) ? Wq : Wk;
#pragma unroll
    for (int kk = 0; kk < 4; kk++) {
      const int ka = kk * 32 + quad * 8;
#pragma unroll
      for (int ct = 0; ct < 8; ct++) {
        bf16x8 wf = *(const bf16x8*)(Wm + (long)h * 16384 + (long)(ct * 16 + n15) * 128 + ka);
        acc[0][ct] = mfma16(af[0][kk], wf, acc[0][ct]);
        acc[1][ct] = mfma16(af[1][kk], wf, acc[1][ct]);
      }
    }
    bf16* oz = ((m == 0) ? qo : ko) + (long)h * 2097152;
    const bf16* Bz = (m == 0) ? Bq : Bk;
    const float sc = (m == 0) ? 0.12751743f : 1.0f;  // (1/sqrt(128))*log2(e)
#pragma unroll
    for (int g = 0; g < 2; g++)
#pragma unroll
      for (int ct = 0; ct < 8; ct++) {
        const int col = ct * 16 + n15;
        const float bv = (float)Bz[h * 128 + col];
#pragma unroll
        for (int r = 0; r < 4; r++)
          oz[(long)(r0 + wr + g * 16 + quad * 4 + r) * 128 + col] = (bf16)((acc[g][ct][r] + bv) * sc);
      }
  }

  // ---- v, transposed store via LDS ----
  {
#pragma unroll
    for (int g = 0; g < 2; g++)
#pragma unroll
      for (int ct = 0; ct < 8; ct++) acc[g][ct] = zz;
#pragma unroll
    for (int kk = 0; kk < 4; kk++) {
      const int ka = kk * 32 + quad * 8;
#pragma unroll
      for (int ct = 0; ct < 8; ct++) {
        bf16x8 wf = *(const bf16x8*)(Wv + (long)h * 16384 + (long)(ct * 16 + n15) * 128 + ka);
        acc[0][ct] = mfma16(af[0][kk], wf, acc[0][ct]);
        acc[1][ct] = mfma16(af[1][kk], wf, acc[1][ct]);
      }
    }
    __syncthreads();   // all waves past their af loads
#pragma unroll
    for (int g = 0; g < 2; g++)
#pragma unroll
      for (int ct = 0; ct < 8; ct++) {
        const int col = ct * 16 + n15;
        const float bv = (float)Bv[h * 128 + col];
#pragma unroll
        for (int r = 0; r < 4; r++)
          tile[col * 136 + (wr + g * 16 + quad * 4 + r)] = (bf16)(acc[g][ct][r] + bv);
      }
    __syncthreads();
    // coalesced copy-out: 16 lanes cover one c-row (128 m = 16 x bf16x8)
    bf16* vz = vo + (long)h * 2097152;
    const int mloc = (threadIdx.x & 15) * 8;
    const int cbase = threadIdx.x >> 4;    // 0..15
#pragma unroll
    for (int cc = 0; cc < 8; cc++) {
      const int c = cc * 16 + cbase;
      *(bf16x8*)&vz[(long)c * 16384 + r0 + mloc] = *(const bf16x8*)&tile[c * 136 + mloc];
    }
  }
}

// flash attention, FAT wave (32 q-rows/wave, 2 row-groups, kf/vf amortized),
// KV tile 64, DOUBLE-BUFFERED lds-direct staging, full KV sweep, normalize +
// write cat in-kernel. Register-pinned 2 waves/SIMD; LDS 80KB -> 2 blocks/CU.
__global__ __launch_bounds__(256, 2) void attn_k(
    const bf16* __restrict__ Q, const bf16* __restrict__ Kg,
    const bf16* __restrict__ vT, bf16* __restrict__ cat)
{
  const int lane = threadIdx.x & 63;
  const int wave = threadIdx.x >> 6;
  const int quad = lane >> 4;
  const int n15 = lane & 15;
  const int b = blockIdx.y, h = blockIdx.z;
  const long qkBase = ((long)h * 4 + b) * 4096 * 128;
  const long vBase = (long)h * (128L * 16384) + (long)b * 4096;
  const int wrow = blockIdx.x * 128 + wave * 32;

  __shared__ bf16 Kt[2][64 * 128];  // addr(kv,c) = kv*128 + ((c>>3 ^ (kv&15))*8) + (c&7)
  __shared__ bf16 Vt[2][128 * 64];  // addr(c,kv) = c*64  + ((kv>>3 ^ (c&7))*8)  + (kv&7)
  __shared__ bf16 Pt[8][1024];      // [wave*2+g]; addr(r,kv) = r*64 + ((kv>>3 ^ (r&7))*8) + (kv&7)

  bf16x8 qf[2][4];
#pragma unroll
  for (int g = 0; g < 2; g++)
#pragma unroll
    for (int kk = 0; kk < 4; kk++)
      qf[g][kk] = *(const bf16x8*)(Q + qkBase + (long)(wrow + g * 16 + n15) * 128 + kk * 32 + quad * 8);

  const int krl  = lane >> 4;
  const int kpch = lane & 15;
  const int vcl  = lane >> 3;
  const int vpch = lane & 7;

  f32x4 Om[2][8] = {};
  float l_part[2][4] = {};

#pragma unroll
  for (int i = 0; i < 4; i++) {
    const int row = wave * 16 + i * 4 + krl;
    const int ch = kpch ^ (row & 15);
    __builtin_amdgcn_global_load_lds(
        (gm_t*)(Kg + qkBase + (long)row * 128 + ch * 8),
        (lds_t*)&Kt[0][(wave * 16 + i * 4) * 128], 16, 0, 0);
  }
#pragma unroll
  for (int i = 0; i < 4; i++) {
    const int c = wave * 32 + i * 8 + vcl;
    const int vch = vpch ^ (c & 7);
    __builtin_amdgcn_global_load_lds(
        (gm_t*)(vT + vBase + (long)c * 16384 + vch * 8),
        (lds_t*)&Vt[0][(wave * 32 + i * 8) * 64], 16, 0, 0);
  }

  for (int it = 0; it < 64; it++) {
    __syncthreads();
    const int cb = it & 1;
    if (it + 1 < 64) {
      const int kv1 = (it + 1) * 64;
      const int nb = cb ^ 1;
#pragma unroll
      for (int i = 0; i < 4; i++) {
        const int row = wave * 16 + i * 4 + krl;
        const int ch = kpch ^ (row & 15);
        __builtin_amdgcn_global_load_lds(
            (gm_t*)(Kg + qkBase + (long)(kv1 + row) * 128 + ch * 8),
            (lds_t*)&Kt[nb][(wave * 16 + i * 4) * 128], 16, 0, 0);
      }
#pragma unroll
      for (int i = 0; i < 4; i++) {
        const int c = wave * 32 + i * 8 + vcl;
        const int vch = vpch ^ (c & 7);
        __builtin_amdgcn_global_load_lds(
            (gm_t*)(vT + vBase + (long)c * 16384 + kv1 + vch * 8),
            (lds_t*)&Vt[nb][(wave * 32 + i * 8) * 64], 16, 0, 0);
      }
    }

    f32x4 S[2][4] = {};
#pragma unroll
    for (int kk = 0; kk < 4; kk++) {
#pragma unroll
      for (int ct = 0; ct < 4; ct++) {
        bf16x8 kf = *(const bf16x8*)&Kt[cb][(ct * 16 + n15) * 128 + (((kk * 4 + quad) ^ n15) * 8)];
        S[0][ct] = mfma16(qf[0][kk], kf, S[0][ct]);
        S[1][ct] = mfma16(qf[1][kk], kf, S[1][ct]);
      }
    }

#pragma unroll
    for (int g = 0; g < 2; g++)
#pragma unroll
      for (int ct = 0; ct < 4; ct++)
#pragma unroll
        for (int r = 0; r < 4; r++) {
          float e = __builtin_amdgcn_exp2f(S[g][ct][r]);
          l_part[g][r] += e;
          const int row = quad * 4 + r;
          const int kv = ct * 16 + n15;
          Pt[wave * 2 + g][row * 64 + ((((kv >> 3) ^ (row & 7)) * 8)) + (kv & 7)] = (bf16)e;
        }

#pragma unroll
    for (int kk = 0; kk < 2; kk++) {
      bf16x8 vf[8];
#pragma unroll
      for (int ct = 0; ct < 8; ct++) {
        const int c = ct * 16 + n15;
        vf[ct] = *(const bf16x8*)&Vt[cb][c * 64 + (((kk * 4 + quad) ^ (c & 7)) * 8)];
      }
#pragma unroll
      for (int g = 0; g < 2; g++) {
        bf16x8 pf = *(const bf16x8*)&Pt[wave * 2 + g][n15 * 64 + (((kk * 4 + quad) ^ (n15 & 7)) * 8)];
#pragma unroll
        for (int ct = 0; ct < 8; ct++)
          Om[g][ct] = mfma16(pf, vf[ct], Om[g][ct]);
      }
    }
  }

#pragma unroll
  for (int g = 0; g < 2; g++) {
    float inv[4];
#pragma unroll
    for (int r = 0; r < 4; r++) {
      float s = l_part[g][r];
#pragma unroll
      for (int off = 1; off < 16; off <<= 1) s += __shfl_xor(s, off);
      inv[r] = 1.f / s;
    }
    const long ob = ((long)b * 4096 + wrow + g * 16 + quad * 4) * 512 + h * 128;
#pragma unroll
    for (int ct = 0; ct < 8; ct++)
#pragma unroll
      for (int r = 0; r < 4; r++)
        cat[ob + (long)r * 512 + ct * 16 + n15] = (bf16)(Om[g][ct][r] * inv[r]);
  }
}

// fused tail, N-SPLIT: block=128 (2 waves share 16 rows; each wave computes
// 64 of the 128 output cols at full K). 1024 blocks -> 2048 waves (8/CU).
// y1 exchanged via LDS; LN partials combined cross-wave via LDS.
__global__ __launch_bounds__(128) void tail_k(
    const bf16* __restrict__ cat,
    const bf16* __restrict__ mhw, const bf16* __restrict__ mhb,
    const bf16* __restrict__ f2w, const bf16* __restrict__ f2b,
    const void* __restrict__ xraw, void* __restrict__ outraw,
    const int* __restrict__ flag)
{
  const int lane = threadIdx.x & 63;
  const int wave = threadIdx.x >> 6;    // 0..1 -> col half
  const int quad = lane >> 4;
  const int n15 = lane & 15;
  const int r0 = blockIdx.x * 16;
  __shared__ bf16 y1t[16][136];
  __shared__ float lred[2][2][16];

  // y1 half: cols wave*64 .. +63, K=512
  f32x4 acc[4] = {};
  for (int k0 = 0; k0 < 512; k0 += 32) {
    const int ka = k0 + quad * 8;
    bf16x8 a0 = *(const bf16x8*)(cat + (long)(r0 + n15) * 512 + ka);
#pragma unroll
    for (int ct = 0; ct < 4; ct++) {
      bf16x8 wf = *(const bf16x8*)(mhw + (long)(wave * 64 + ct * 16 + n15) * 512 + ka);
      acc[ct] = mfma16(a0, wf, acc[ct]);
    }
  }
#pragma unroll
  for (int ct = 0; ct < 4; ct++) {
    const int col = wave * 64 + ct * 16 + n15;
    const float bv = (float)mhb[col];
#pragma unroll
    for (int r = 0; r < 4; r++)
      y1t[quad * 4 + r][col] = (bf16)(acc[ct][r] + bv);
  }
  __syncthreads();

  // y2 half: cols wave*64 .. +63, K=128 (full y1 from LDS)
  f32x4 acc2[4] = {};
  for (int k0 = 0; k0 < 128; k0 += 32) {
    const int ka = k0 + quad * 8;
    bf16x8 a0 = *(const bf16x8*)&y1t[n15][ka];
#pragma unroll
    for (int ct = 0; ct < 4; ct++) {
      bf16x8 wf = *(const bf16x8*)(f2w + (long)(wave * 64 + ct * 16 + n15) * 128 + ka);
      acc2[ct] = mfma16(a0, wf, acc2[ct]);
    }
  }

  float s1[4] = {}, s2[4] = {};
#pragma unroll
  for (int ct = 0; ct < 4; ct++) {
    const float bv = (float)f2b[wave * 64 + ct * 16 + n15];
#pragma unroll
    for (int r = 0; r < 4; r++) {
      const float v = acc2[ct][r] + bv;
      acc2[ct][r] = v;
      s1[r] += v;
      s2[r] += v * v;
    }
  }
#pragma unroll
  for (int r = 0; r < 4; r++) {
    float a = s1[r], b2 = s2[r];
#pragma unroll
    for (int off = 1; off < 16; off <<= 1) {
      a += __shfl_xor(a, off);
      b2 += __shfl_xor(b2, off);
    }
    if (n15 == 0) { lred[wave][0][quad * 4 + r] = a; lred[wave][1][quad * 4 + r] = b2; }
  }
  __syncthreads();

  const int isF32 = *flag;
#pragma unroll
  for (int r = 0; r < 4; r++) {
    const int row = quad * 4 + r;
    const float tot = lred[0][0][row] + lred[1][0][row];
    const float tot2 = lred[0][1][row] + lred[1][1][row];
    const float mu = tot * (1.f / 128.f);
    const float var = fmaxf(tot2 * (1.f / 128.f) - mu * mu, 0.f);
    const float inv = rsqrtf(var + 1e-5f);
#pragma unroll
    for (int ct = 0; ct < 4; ct++) {
      const long idx = (long)(r0 + row) * 128 + wave * 64 + ct * 16 + n15;
      const float resid = isF32 ? ((const float*)xraw)[idx]
                                : (float)((const bf16*)xraw)[idx];
      const float v = (acc2[ct][r] - mu) * inv + resid;
      if (isF32) ((float*)outraw)[idx] = v;
      else       ((bf16*)outraw)[idx] = (bf16)v;
    }
  }
}

extern "C" void kernel_launch(void* const* d_in, const int* in_sizes, int n_in,
                              void* d_out, int out_size, void* d_ws, size_t ws_size,
                              hipStream_t stream)
{
  bf16* ws  = (bf16*)d_ws;
  bf16* q   = ws;                     // 8388608 elems [h][m][c]
  bf16* kb  = ws + 8388608;           // 8388608
  bf16* vt  = ws + 16777216;          // 8388608 (vT[h][c][m])
  bf16* cat = ws + 25165824;          // 8388608 (16384 x 512)
  const long AR = 33554432;           // bf16 canonical arena (2511616 elems)
  int* flag = (int*)(ws + 36066048);

  static const int counts[N_SEG] = {2097152, 49152, 16384, 128, 65536, 512, 65536, 512,
                                    65536, 512, 1536, 512, 65536, 512, 65536, 512, 16384, 128};
  long offs[N_SEG]; long o = AR;
  for (int i = 0; i < N_SEG; i++) { offs[i] = o; o += counts[i]; }
  bf16* xc    = ws + offs[0];
  bf16* pc    = ws + offs[1];
  bf16* f1w   = ws + offs[2];
  bf16* f1b   = ws + offs[3];
  bf16* hqw   = ws + offs[4];
  bf16* hqb   = ws + offs[5];
  bf16* hkw   = ws + offs[6];
  bf16* hkb   = ws + offs[7];
  bf16* hvw   = ws + offs[8];
  bf16* hvb   = ws + offs[9];
  bf16* pe1w  = ws + offs[10];
  bf16* pe1b  = ws + offs[11];
  bf16* pe2w  = ws + offs[12];
  bf16* pe2b  = ws + offs[13];
  bf16* mhw   = ws + offs[14];
  bf16* mhb   = ws + offs[15];
  bf16* f2w   = ws + offs[16];
  bf16* f2b   = ws + offs[17];

  ConvArgs ca;
  for (int i = 0; i < N_SEG; i++) ca.src[i] = d_in[i];
  convall_k<<<dim3((TOTAL_CONV + 49152 + 2047) / 2048), dim3(256), 0, stream>>>(ca, ws + AR, d_out, flag);

  // q uses hk_w, k uses hq_w (reference name swap)
  pre_k<<<dim3(128, 4), dim3(256), 0, stream>>>(xc, pc, f1w, f1b, pe1w, pe1b, pe2w, pe2b,
                                                hkw, hkb, hqw, hqb, hvw, hvb, q, kb, vt);
  attn_k<<<dim3(32, 4, 4), dim3(256), 0, stream>>>(q, kb, vt, cat);
  tail_k<<<dim3(1024), dim3(128), 0, stream>>>(cat, mhw, mhb, f2w, f2b, d_in[0], d_out, flag);
}